// Round 10
// baseline (144.824 us; speedup 1.0000x reference)
//
#include <hip/hip_runtime.h>
#include <hip/hip_bf16.h>

typedef __attribute__((ext_vector_type(8))) short bf16x8;
typedef __attribute__((ext_vector_type(4))) short bf16x4;
typedef __attribute__((ext_vector_type(4))) float f32x4;
typedef __attribute__((ext_vector_type(4))) unsigned short u16x4;
typedef __attribute__((ext_vector_type(8))) unsigned short u16x8;

// NOTE: no __has_builtin guards — they return false for aux-target builtins
// in the HIP host pass (that's what broke R8). Direct use compiles in both.
#define MFMA16(a, b, c) __builtin_amdgcn_mfma_f32_16x16x16bf16_1k(a, b, c, 0, 0, 0)
#define EXP2f(x) exp2f(x)

// Q pre-scale: (1/8) * log2(e)  -> scores arrive in log2 domain, exp = v_exp_f32
#define SCALE_Q 0.18033688011112042f

// ws layout (ushort units):
//   Qb [4][4096][8]  @ 0        bf16, pre-scaled by SCALE_Q, [n][c]
//   Kb [4][4096][8]  @ 131072   bf16, [m][c]
//   Vb [4][64][4096] @ 262144   bf16, [v][n]
//   avg floats [4][64] @ ushort offset 1310720 (zeroed via memsetAsync)
#define WS_QB 0
#define WS_KB 131072
#define WS_VB 262144
#define WS_AVG_U 1310720

__device__ __forceinline__ unsigned short bf_hi(float x) {
    __hip_bfloat16 h = __float2bfloat16(x);
    return *reinterpret_cast<unsigned short*>(&h);
}
__device__ __forceinline__ unsigned int bfpk(float lo, float hi) {
    return (unsigned int)bf_hi(lo) | ((unsigned int)bf_hi(hi) << 16);
}

// ---------------------------------------------------------------------------
// Kernel A: QKV projection (MFMA) + channel means. grid = 1280 x 256.
// ---------------------------------------------------------------------------
__global__ __launch_bounds__(256) void proj_kernel(
    const float* __restrict__ x,
    const float* __restrict__ Wq, const float* __restrict__ bq,
    const float* __restrict__ Wk, const float* __restrict__ bk,
    const float* __restrict__ Wv, const float* __restrict__ bv,
    unsigned short* __restrict__ Qb, unsigned short* __restrict__ Kb,
    unsigned short* __restrict__ Vb, float* __restrict__ avg)
{
    __shared__ __align__(16) unsigned short Wls[16 * 72];

    const int tid = threadIdx.x;
    const int w = tid >> 6;
    const int l = tid & 63;
    const int g = l >> 4;
    const int l15 = l & 15;

    const int tile = blockIdx.x >> 8;
    const int pair = blockIdx.x & 255;
    const int b = pair >> 6;
    const int n0 = (pair & 63) << 6;
    const int n = n0 + w * 16 + l15;
    const float* xb = x + b * 262144;

    float xr[2][8];
#pragma unroll
    for (int kcb = 0; kcb < 2; ++kcb)
#pragma unroll
        for (int j = 0; j < 8; ++j)
            xr[kcb][j] = xb[(kcb * 32 + g * 8 + j) * 4096 + n];

#pragma unroll
    for (int i = 0; i < 4; ++i) {
        const int idx = i * 256 + tid;
        const int row = idx >> 6, col = idx & 63;
        float wv;
        if (tile == 0) wv = (row < 8) ? Wq[row * 64 + col] : Wk[(row - 8) * 64 + col];
        else           wv = Wv[((tile - 1) * 16 + row) * 64 + col];
        Wls[row * 72 + col] = bf_hi(wv);
    }
    __syncthreads();

    bf16x8 bfr[2];
#pragma unroll
    for (int kcb = 0; kcb < 2; ++kcb)
#pragma unroll
        for (int j = 0; j < 8; ++j)
            bfr[kcb][j] = (short)bf_hi(xr[kcb][j]);

    const bf16x8 a0 = *(const bf16x8*)&Wls[l15 * 72 + g * 8];
    const bf16x8 a1 = *(const bf16x8*)&Wls[l15 * 72 + 32 + g * 8];
    f32x4 acc;
#pragma unroll
    for (int r = 0; r < 4; ++r) acc[r] = 0.0f;
    acc = __builtin_amdgcn_mfma_f32_16x16x32_bf16(a0, bfr[0], acc, 0, 0, 0);
    acc = __builtin_amdgcn_mfma_f32_16x16x32_bf16(a1, bfr[1], acc, 0, 0, 0);

    if (tile == 0) {
        u16x4 ov;
        if (g < 2) {
#pragma unroll
            for (int r = 0; r < 4; ++r) ov[r] = bf_hi((acc[r] + bq[g * 4 + r]) * SCALE_Q);
            *(u16x4*)&Qb[(b * 4096 + n) * 8 + g * 4] = ov;
        } else {
#pragma unroll
            for (int r = 0; r < 4; ++r) ov[r] = bf_hi(acc[r] + bk[(g - 2) * 4 + r]);
            *(u16x4*)&Kb[(b * 4096 + n) * 8 + (g - 2) * 4] = ov;
        }
        const int c = tid >> 2;
        const float* xrow = xb + c * 4096 + n0 + ((tid & 3) << 4);
        float s = 0.0f;
#pragma unroll
        for (int k = 0; k < 4; ++k) {
            const float4 v = *(const float4*)&xrow[k * 4];
            s += (v.x + v.y) + (v.z + v.w);
        }
        s += __shfl_xor(s, 1);
        s += __shfl_xor(s, 2);
        if ((tid & 3) == 0) atomicAdd(&avg[b * 64 + c], s * (1.0f / 4096.0f));
    } else {
#pragma unroll
        for (int r = 0; r < 4; ++r) {
            const int v = (tile - 1) * 16 + g * 4 + r;
            Vb[(b * 64 + v) * 4096 + n] = bf_hi(acc[r] + bv[v]);
        }
    }
}

// ---------------------------------------------------------------------------
// Kernel B: attention + gate. grid = 512 (XCD-chunk-swizzled), 512 thr/8 waves.
// All-16x16x16 pipeline: QK D-layout (row=g*4+r, col=l15) IS the PV B-frag
// layout (k=g*4..+3, col=l15) -> P goes QK->exp->cvt_pk->PV entirely in
// registers, no cross-lane ops, no in-loop LDS/barriers. Dual A/B register
// sets keep 2 chunks of K/V loads in flight; compiler free to overlap chunks.
// ---------------------------------------------------------------------------
__global__ __launch_bounds__(512, 4) void attn_kernel(
    const unsigned short* __restrict__ Qb, const unsigned short* __restrict__ Kb,
    const unsigned short* __restrict__ Vb, const float* __restrict__ avg,
    const float* __restrict__ W1, const float* __restrict__ b1,
    const float* __restrict__ W2, const float* __restrict__ b2,
    float* __restrict__ out)
{
    __shared__ float osum[4][64][33];   // [wave 0-3][v][q+pad]; waves 4-7 add in
    __shared__ float zls[32], gls[64], avgs[64];

    const int t = threadIdx.x;
    const int w = t >> 6;
    const int l = t & 63;
    const int g = l >> 4;
    const int l15 = l & 15;
    const bool gk = (g < 2);
    const int g4 = g * 4;

    // bijective XCD chunk swizzle (512 % 8 == 0)
    const int wg = (blockIdx.x & 7) * 64 + (blockIdx.x >> 3);
    const int b = wg >> 7;
    const int q0 = (wg & 127) << 5;

    if (t < 32) zls[t] = 0.0f;
    if (t < 64) avgs[t] = avg[b * 64 + t];
    __syncthreads();   // init visible before post-loop atomics/reads

    const bf16x4 zf4 = {};
    // Q B-frags: k = ch g*4..+3 (zero for g>=2), col = q
    bf16x4 qf[2];
#pragma unroll
    for (int qt = 0; qt < 2; ++qt) {
        bf16x4 v = *(const bf16x4*)&Qb[(b * 4096 + q0 + qt * 16 + l15) * 8 + g4];
        qf[qt] = gk ? v : zf4;
    }

    const unsigned short* kb = Kb + b * 4096 * 8;
    const unsigned short* vr0 = Vb + (b * 64 + l15) * 4096;        // vt=0 row
    const unsigned short* vrow[4] = { vr0, vr0 + 16 * 4096, vr0 + 32 * 4096, vr0 + 48 * 4096 };

    f32x4 acc[2][4];
#pragma unroll
    for (int qt = 0; qt < 2; ++qt)
#pragma unroll
        for (int vt = 0; vt < 4; ++vt)
#pragma unroll
            for (int r = 0; r < 4; ++r) acc[qt][vt][r] = 0.0f;
    float zreg[2] = {0.f, 0.f};

    // K A-frags: row = m (l15 within mt-block), k = ch g*4..+3 (zero g>=2)
    // V A-frags: row = v, k = m-slice g*4..+3 within each 16-m block
#define RELOAD(KP, VP, M0)                                                   \
    {                                                                        \
        bf16x4 kv0 = *(const bf16x4*)&kb[((M0) + l15) * 8 + g4];             \
        bf16x4 kv1 = *(const bf16x4*)&kb[((M0) + 16 + l15) * 8 + g4];        \
        KP[0] = gk ? kv0 : zf4;                                              \
        KP[1] = gk ? kv1 : zf4;                                              \
        _Pragma("unroll")                                                    \
        for (int vt = 0; vt < 4; ++vt) {                                     \
            VP[vt][0] = *(const bf16x4*)&vrow[vt][(M0) + g4];                \
            VP[vt][1] = *(const bf16x4*)&vrow[vt][(M0) + 16 + g4];           \
        }                                                                    \
    }

#define CHUNK(KP, VP)                                                        \
    {                                                                        \
        const f32x4 dz = {0.f, 0.f, 0.f, 0.f};                               \
        bf16x4 pb[2][2];                                                     \
        _Pragma("unroll")                                                    \
        for (int mt = 0; mt < 2; ++mt) {                                     \
            _Pragma("unroll")                                                \
            for (int qt = 0; qt < 2; ++qt) {                                 \
                f32x4 d = MFMA16(KP[mt], qf[qt], dz);                        \
                float p0 = EXP2f(d[0]), p1 = EXP2f(d[1]);                    \
                float p2 = EXP2f(d[2]), p3 = EXP2f(d[3]);                    \
                zreg[qt] += (p0 + p1) + (p2 + p3);                           \
                union { unsigned int u[2]; bf16x4 v; } pw;                   \
                pw.u[0] = bfpk(p0, p1);                                      \
                pw.u[1] = bfpk(p2, p3);                                      \
                pb[mt][qt] = pw.v;                                           \
            }                                                                \
        }                                                                    \
        _Pragma("unroll")                                                    \
        for (int vt = 0; vt < 4; ++vt) {                                     \
            _Pragma("unroll")                                                \
            for (int mt = 0; mt < 2; ++mt) {                                 \
                acc[0][vt] = MFMA16(VP[vt][mt], pb[mt][0], acc[0][vt]);      \
                acc[1][vt] = MFMA16(VP[vt][mt], pb[mt][1], acc[1][vt]);      \
            }                                                                \
        }                                                                    \
    }

    bf16x4 kpA[2], kpB[2];
    bf16x4 vpA[4][2], vpB[4][2];
    int mA = w * 32;          // chunk ci: m0 = (w + 8*ci)*32 = w*32 + ci*256
    int mB = w * 32 + 256;
    RELOAD(kpA, vpA, mA);
    RELOAD(kpB, vpB, mB);

#pragma unroll 1
    for (int it = 0; it < 8; ++it) {
        CHUNK(kpA, vpA);
        mA += 512;            // final reload reads past-end (stays in d_ws), unused
        RELOAD(kpA, vpA, mA);
        CHUNK(kpB, vpB);
        mB += 512;
        RELOAD(kpB, vpB, mB);
    }

    // z: combine over g-lanes, one atomic per wave per q
#pragma unroll
    for (int qt = 0; qt < 2; ++qt) {
        float z = zreg[qt];
        z += __shfl_xor(z, 16);
        z += __shfl_xor(z, 32);
        if (g == 0) atomicAdd(&zls[qt * 16 + l15], z);
    }

    // stage 1: waves 0-3 write partial O
    if (w < 4) {
#pragma unroll
        for (int qt = 0; qt < 2; ++qt)
#pragma unroll
            for (int vt = 0; vt < 4; ++vt)
#pragma unroll
                for (int r = 0; r < 4; ++r)
                    osum[w][vt * 16 + g4 + r][qt * 16 + l15] = acc[qt][vt][r];
    }
    // SE gate (wave 0 lanes, tiny)
    if (t < 64) {
        float hreg[4];
#pragma unroll
        for (int j = 0; j < 4; ++j) {
            float hh = b1[j];
            for (int c = 0; c < 64; ++c) hh += W1[j * 64 + c] * avgs[c];
            hreg[j] = fmaxf(hh, 0.0f);
        }
        float gg = b2[t];
#pragma unroll
        for (int j = 0; j < 4; ++j) gg += W2[t * 4 + j] * hreg[j];
        gls[t] = 1.0f / (1.0f + __expf(-gg));
    }
    __syncthreads();

    // stage 2: waves 4-7 add their partials
    if (w >= 4) {
#pragma unroll
        for (int qt = 0; qt < 2; ++qt)
#pragma unroll
            for (int vt = 0; vt < 4; ++vt)
#pragma unroll
                for (int r = 0; r < 4; ++r)
                    osum[w - 4][vt * 16 + g4 + r][qt * 16 + l15] += acc[qt][vt][r];
    }
    __syncthreads();

    // combine 4 partials + scale + gate + store (512 threads, 4 q each)
    {
        const int v = t >> 3;
        const int qb4 = (t & 7) * 4;
        const float gv = gls[v];
        float* orow = out + (b * 64 + v) * 4096 + q0 + qb4;
#pragma unroll
        for (int j = 0; j < 4; ++j) {
            const int q = qb4 + j;
            const float s = (osum[0][v][q] + osum[1][v][q])
                          + (osum[2][v][q] + osum[3][v][q]);
            orow[j] = s * (1.0f / zls[q]) * gv;
        }
    }
#undef RELOAD
#undef CHUNK
}

extern "C" void kernel_launch(void* const* d_in, const int* in_sizes, int n_in,
                              void* d_out, int out_size, void* d_ws, size_t ws_size,
                              hipStream_t stream) {
    const float* x  = (const float*)d_in[0];
    const float* Wq = (const float*)d_in[1];
    const float* bq = (const float*)d_in[2];
    const float* Wk = (const float*)d_in[3];
    const float* bk = (const float*)d_in[4];
    const float* Wv = (const float*)d_in[5];
    const float* bv = (const float*)d_in[6];
    const float* W1 = (const float*)d_in[7];
    const float* b1 = (const float*)d_in[8];
    const float* W2 = (const float*)d_in[9];
    const float* b2 = (const float*)d_in[10];

    unsigned short* wsu = (unsigned short*)d_ws;
    unsigned short* Qb = wsu + WS_QB;
    unsigned short* Kb = wsu + WS_KB;
    unsigned short* Vb = wsu + WS_VB;
    float* avg = (float*)(wsu + WS_AVG_U);
    float* out = (float*)d_out;

    (void)hipMemsetAsync(avg, 0, 256 * sizeof(float), stream);
    proj_kernel<<<1280, 256, 0, stream>>>(x, Wq, bq, Wk, bk, Wv, bv, Qb, Kb, Vb, avg);
    attn_kernel<<<512, 512, 0, stream>>>(Qb, Kb, Vb, avg, W1, b1, W2, b2, out);
}